// Round 23
// baseline (187.715 us; speedup 1.0000x reference)
//
#include <hip/hip_runtime.h>
#include <hip/hip_bf16.h>

#define B_ 4
#define T_ 2048
#define C_ 1024
#define H_ 16
#define HD_ 64
#define BT_ (B_*T_)            // 8192
#define C3_ (3*C_)             // 3072
#define BHTD_ ((size_t)B_*H_*T_*HD_)  // 8388608 elements per q/k/v

// softmax scale 1/8 with log2(e) folded in (attention uses exp2)
#define QSCALE 0.18033688011112042f

using u16 = unsigned short;
using u32 = unsigned int;
using bf16x8 = __attribute__((ext_vector_type(8))) short;
using f32x4  = __attribute__((ext_vector_type(4))) float;
using f32x16 = __attribute__((ext_vector_type(16))) float;
using u16x4  = __attribute__((ext_vector_type(4))) u16;
typedef int i32x2 __attribute__((ext_vector_type(2)));

#if __has_builtin(__builtin_amdgcn_exp2f)
#define EXP2(x) __builtin_amdgcn_exp2f(x)
#else
#define EXP2(x) exp2f(x)
#endif

__device__ __forceinline__ u16 f2bf(float f) {
  u32 u = __float_as_uint(f);
  u += 0x7fffu + ((u >> 16) & 1u);   // round-to-nearest-even
  return (u16)(u >> 16);
}

__device__ __forceinline__ float bf2f(u16 v) {
  return __uint_as_float(((u32)v) << 16);
}

// v_cvt_pk_bf16_f32: one instruction packs two f32 -> two bf16 (RTNE)
__device__ __forceinline__ u32 cvtpk(float lo, float hi) {
  u32 r;
  asm("v_cvt_pk_bf16_f32 %0, %1, %2" : "=v"(r) : "v"(lo), "v"(hi));
  return r;
}

// exchange with the lane^32 partner
__device__ __forceinline__ void plswap(u32 &a, u32 &b) {
#if __has_builtin(__builtin_amdgcn_permlane32_swap)
  i32x2 r = __builtin_amdgcn_permlane32_swap((int)a, (int)b, false, false);
  a = (u32)r[0]; b = (u32)r[1];
#else
  asm volatile("v_permlane32_swap_b32 %0, %1" : "+v"(a), "+v"(b));
#endif
}

__device__ __forceinline__ float xmaxf(float x) {
  u32 a = __float_as_uint(x), b = a;
  plswap(a, b);
  return fmaxf(__uint_as_float(a), __uint_as_float(b));
}
__device__ __forceinline__ float xaddf(float x) {
  u32 a = __float_as_uint(x), b = a;
  plswap(a, b);
  return __uint_as_float(a) + __uint_as_float(b);
}

__device__ __forceinline__ void gload16(const void* g,
                                        __attribute__((address_space(3))) void* l) {
  __builtin_amdgcn_global_load_lds((const __attribute__((address_space(1))) void*)g,
                                   l, 16, 0, 0);
}

// ---------------- fused prep: x->bf16  +  w_attn^T  +  w_proj^T (one launch) ----------------
__global__ __launch_bounds__(256) void k_prep(const float* __restrict__ x,
                                              u16* __restrict__ xbf,
                                              const float* __restrict__ w_attn,
                                              u16* __restrict__ wat,
                                              const float* __restrict__ w_proj,
                                              u16* __restrict__ wpt) {
  __shared__ float t[32][33];
  int fb = blockIdx.x;
  if (fb < 8192) {
    size_t i = ((size_t)fb * 256 + threadIdx.x) * 4;
    f32x4 f = *(const f32x4*)(x + i);
    u16x4 o;
    o[0] = f2bf(f[0]); o[1] = f2bf(f[1]); o[2] = f2bf(f[2]); o[3] = f2bf(f[3]);
    *(u16x4*)(xbf + i) = o;
    return;
  }
  const float* w; u16* wt; int K, N, n0, k0;
  if (fb < 8192 + 3072) {
    int tb = fb - 8192;
    w = w_attn; wt = wat; K = C_; N = C3_;
    n0 = (tb % 96) * 32; k0 = (tb / 96) * 32;
  } else {
    int tb = fb - 8192 - 3072;
    w = w_proj; wt = wpt; K = C_; N = C_;
    n0 = (tb % 32) * 32; k0 = (tb / 32) * 32;
  }
  int tx = threadIdx.x & 31;
  int ty = threadIdx.x >> 5;   // 0..7
  #pragma unroll
  for (int r = 0; r < 4; ++r)
    t[ty + r*8][tx] = w[(size_t)(k0 + ty + r*8) * N + n0 + tx];
  __syncthreads();
  #pragma unroll
  for (int r = 0; r < 4; ++r)
    wt[(size_t)(n0 + ty + r*8) * K + k0 + tx] = f2bf(t[tx][ty + r*8]);
}

// ---------------- transpose V: qkv3[B*T][3C] (V slice) -> vT [B,H,HD,T] ----------------
__global__ __launch_bounds__(256) void k_transpose_v(const u16* __restrict__ qkv3,
                                                     u16* __restrict__ dst) {
  __shared__ u16 t[64][72];
  int bh = blockIdx.y;
  int bb = bh >> 4, hh = bh & 15;
  int t0 = blockIdx.x * 64;
  const u16* s = qkv3 + (size_t)(bb*T_)*C3_ + 2*C_ + hh*64;   // V slice, row stride 3C
  u16* d = dst + (size_t)bh * HD_ * T_;
  int r = threadIdx.x >> 2, c0 = (threadIdx.x & 3) * 16;
  bf16x8 a0 = *(const bf16x8*)(s + (size_t)(t0 + r)*C3_ + c0);
  bf16x8 a1 = *(const bf16x8*)(s + (size_t)(t0 + r)*C3_ + c0 + 8);
  #pragma unroll
  for (int j = 0; j < 8; ++j) t[r][c0 + j] = (u16)a0[j];
  #pragma unroll
  for (int j = 0; j < 8; ++j) t[r][c0 + 8 + j] = (u16)a1[j];
  __syncthreads();
  bf16x8 b0, b1;
  #pragma unroll
  for (int j = 0; j < 8; ++j) b0[j] = (short)t[c0 + j][r];
  #pragma unroll
  for (int j = 0; j < 8; ++j) b1[j] = (short)t[c0 + 8 + j][r];
  *(bf16x8*)(d + (size_t)r*T_ + t0 + c0) = b0;
  *(bf16x8*)(d + (size_t)r*T_ + t0 + c0 + 8) = b1;
}

// ---------------- bf16 MFMA GEMM: 256x128 tile, BK=64, 8 waves (validated r22) ----------------
template<int EPI, int K>
__global__ __launch_bounds__(512) void k_gemm(const u16* __restrict__ A,
                                              const u16* __restrict__ Bt,
                                              const float* __restrict__ bias,
                                              void* __restrict__ outp) {
  __shared__ __align__(16) u16 lA[256*64];   // 32 KB
  __shared__ __align__(16) u16 lB[128*64];   // 16 KB
  int tid = threadIdx.x;
  int wave = tid >> 6, lane = tid & 63;
  int wr = wave >> 1, wc = wave & 1;         // wr 0..3 (rows), wc 0..1 (cols)
  int lrow = lane & 15, lgrp = lane >> 4;
  int bidf = blockIdx.y * gridDim.x + blockIdx.x;
  int xcd = bidf & 7, loc = bidf >> 3;       // consecutive blocks round-robin XCDs
  int ypx = gridDim.y >> 3;                  // by-rows per XCD chunk
  int bx = loc / ypx;                        // column-major within chunk
  int by = xcd * ypx + (loc % ypx);
  int row0 = by * 256, col0 = bx * 128;

  f32x4 zero = {0.f, 0.f, 0.f, 0.f};
  f32x4 acc[4][4];
  #pragma unroll
  for (int m = 0; m < 4; ++m)
    #pragma unroll
    for (int n = 0; n < 4; ++n) acc[m][n] = zero;

  for (int kt = 0; kt < K; kt += 64) {
    #pragma unroll
    for (int it = 0; it < 4; ++it) {
      int c = tid + it*512;             // 16B chunk 0..2047
      int r = c >> 3, sl = c & 7;       // row, logical slot
      int sk = sl ^ (r & 7);            // pre-swizzled SOURCE slot (LDS linear)
      gload16(A + (size_t)(row0 + r)*K + kt + sk*8,
              (__attribute__((address_space(3))) char*)lA + it*8192 + wave*1024);
    }
    #pragma unroll
    for (int it = 0; it < 2; ++it) {
      int c = tid + it*512;             // 16B chunk 0..1023
      int r = c >> 3, sl = c & 7;
      int sk = sl ^ (r & 7);
      gload16(Bt + (size_t)(col0 + r)*K + kt + sk*8,
              (__attribute__((address_space(3))) char*)lB + it*8192 + wave*1024);
    }
    __syncthreads();
    #pragma unroll
    for (int kk = 0; kk < 2; ++kk) {
      bf16x8 af[4], bfr[4];
      #pragma unroll
      for (int m = 0; m < 4; ++m) {
        int row = wr*64 + m*16 + lrow;
        af[m] = *(const bf16x8*)(lA + row*64 + (((kk*4 + lgrp) ^ (row & 7)))*8);
      }
      #pragma unroll
      for (int n = 0; n < 4; ++n) {
        int row = wc*64 + n*16 + lrow;
        bfr[n] = *(const bf16x8*)(lB + row*64 + (((kk*4 + lgrp) ^ (row & 7)))*8);
      }
      #pragma unroll
      for (int m = 0; m < 4; ++m)
        #pragma unroll
        for (int n = 0; n < 4; ++n)
          acc[m][n] = __builtin_amdgcn_mfma_f32_16x16x32_bf16(af[m], bfr[n], acc[m][n], 0, 0, 0);
    }
    __syncthreads();
  }

  #pragma unroll
  for (int m = 0; m < 4; ++m) {
    #pragma unroll
    for (int n = 0; n < 4; ++n) {
      int gcol = col0 + wc*64 + n*16 + lrow;
      float bv = bias[gcol];
      #pragma unroll
      for (int r = 0; r < 4; ++r) {
        int grow = row0 + wr*64 + m*16 + lgrp*4 + r;
        float val = acc[m][n][r] + bv;
        if (EPI == 0) {
          if (gcol < C_) val *= QSCALE;   // fold softmax scale * log2(e) into q
          ((u16*)outp)[(size_t)grow*C3_ + gcol] = f2bf(val);   // coalesced [M][3C]
        } else {
          ((float*)outp)[(size_t)grow*C_ + gcol] = val;
        }
      }
    }
  }
}

// ---------------- causal flash attention: split-KV, LDS-shared, partial outputs ----------------
// 1024 blocks = head(64) x pair(8) x half(2). Pair = q-tiles (jA, 15-jA); split point
// s = (jA<=3 ? 15-2jA : 8) makes every block 16-18 steps (uniform) -> 4 blocks/CU
// (2x TLP vs r22). Each half computes partial (O, m, l) over its KV range and writes
// them to workspace (bf16 O, f32 m/l); k_merge combines. Protocol identical to r22:
// reg-staged double-buffer + plain __syncthreads, T14 issue-early.
__global__ __launch_bounds__(256, 2) void k_attn(const u16* __restrict__ qkv3,
                                                 const u16* __restrict__ vt,
                                                 u16* __restrict__ pO0,
                                                 u16* __restrict__ pO1,
                                                 float* __restrict__ pml) {
  __shared__ __align__(16) u16 Kl[2][64][72];   // 18.4 KB (padded rows)
  __shared__ __align__(16) u16 Vl[2][64][72];   // 18.4 KB
  int tid = threadIdx.x;
  int wave = tid >> 6, lane = tid & 63;
  int l31 = lane & 31, hi = lane >> 5;
  int bid = blockIdx.x;
  int head = bid & 63;                 // bid&7 = head&7 -> stable XCD group per head
  int jA = (bid >> 6) & 7;             // pair (jA, 15-jA)
  int half = bid >> 9;                 // 0 or 1
  int jB = 15 - jA;
  int bidx = head >> 4, hh = head & 15;
  const u16* qb = qkv3 + (size_t)(bidx*T_)*C3_ + hh*64;        // row stride 3C
  const u16* kb = qkv3 + (size_t)(bidx*T_)*C3_ + C_ + hh*64;   // row stride 3C
  const u16* vb = vt + (size_t)head * HD_ * T_;                // [HD][T]
  u16* pO = half ? pO1 : pO0;

  int sr = tid >> 2;            // staging row 0..63
  int sc = (tid & 3) * 16;      // staging col (u16 units)

  f32x16 zero16 = {0.f,0.f,0.f,0.f,0.f,0.f,0.f,0.f,0.f,0.f,0.f,0.f,0.f,0.f,0.f,0.f};

  int qr0A = jA*128 + wave*32, qr0B = jB*128 + wave*32;
  bf16x8 qfA[4], qfB[4];
  {
    const u16* qrowA = qb + (size_t)(qr0A + l31)*C3_ + hi*8;
    const u16* qrowB = qb + (size_t)(qr0B + l31)*C3_ + hi*8;
    #pragma unroll
    for (int i = 0; i < 4; ++i) { qfA[i] = *(const bf16x8*)(qrowA + 16*i);
                                  qfB[i] = *(const bf16x8*)(qrowB + 16*i); }
  }
  f32x16 oA0 = zero16, oA1 = zero16, oB0 = zero16, oB1 = zero16;
  float mrunA = -1e30f, lrunA = 0.f, mrunB = -1e30f, lrunB = 0.f;
  int qgA = qr0A + l31, qgB = qr0B + l31;
  int ntA = 2*jA + 2, ntB = 32 - 2*jA;
  int sp = (jA <= 3) ? (15 - 2*jA) : 8;   // balanced split point
  int tbeg = half ? sp : 0;
  int tend = half ? ntB : sp;

  auto step = [&](bf16x8 (&qf)[4], f32x16 &od0, f32x16 &od1,
                  float &mrun, float &lrun, int qg, int qr0, int kv0, int cb) {
    if (kv0 > qr0 + 31) return;          // wave-uniform: fully-masked tile
    bf16x8 kf[8], vf[8];
    #pragma unroll
    for (int i = 0; i < 4; ++i) {
      int cc = 16*i + 8*hi;
      kf[i]     = *(const bf16x8*)&Kl[cb][l31][cc];
      kf[4 + i] = *(const bf16x8*)&Kl[cb][l31 + 32][cc];
      vf[i]     = *(const bf16x8*)&Vl[cb][l31][cc];
      vf[4 + i] = *(const bf16x8*)&Vl[cb][l31 + 32][cc];
    }

    f32x16 s0 = zero16, s1 = zero16;
    __builtin_amdgcn_s_setprio(1);
    s0 = __builtin_amdgcn_mfma_f32_32x32x16_bf16(kf[0], qf[0], s0, 0, 0, 0);
    s1 = __builtin_amdgcn_mfma_f32_32x32x16_bf16(kf[4], qf[0], s1, 0, 0, 0);
    s0 = __builtin_amdgcn_mfma_f32_32x32x16_bf16(kf[1], qf[1], s0, 0, 0, 0);
    s1 = __builtin_amdgcn_mfma_f32_32x32x16_bf16(kf[5], qf[1], s1, 0, 0, 0);
    s0 = __builtin_amdgcn_mfma_f32_32x32x16_bf16(kf[2], qf[2], s0, 0, 0, 0);
    s1 = __builtin_amdgcn_mfma_f32_32x32x16_bf16(kf[6], qf[2], s1, 0, 0, 0);
    s0 = __builtin_amdgcn_mfma_f32_32x32x16_bf16(kf[3], qf[3], s0, 0, 0, 0);
    s1 = __builtin_amdgcn_mfma_f32_32x32x16_bf16(kf[7], qf[3], s1, 0, 0, 0);
    __builtin_amdgcn_s_setprio(0);

    if (kv0 + 63 > qr0) {      // diagonal tile: apply causal mask
      #pragma unroll
      for (int r = 0; r < 16; ++r) {
        int kl2 = (r & 3) + 8*(r >> 2) + 4*hi;
        if (kv0 + kl2      > qg) s0[r] = -1e30f;
        if (kv0 + 32 + kl2 > qg) s1[r] = -1e30f;
      }
    }

    float tmx[16];
    #pragma unroll
    for (int i = 0; i < 16; ++i) tmx[i] = fmaxf(s0[i], s1[i]);
    #pragma unroll
    for (int off = 8; off > 0; off >>= 1)
      #pragma unroll
      for (int i = 0; i < 8; ++i)
        if (i < off) tmx[i] = fmaxf(tmx[i], tmx[i + off]);
    float pmax = xmaxf(tmx[0]);

    if (!__all(pmax <= mrun)) {
      float mnew = fmaxf(mrun, pmax);
      float ex = EXP2(mrun - mnew);
      mrun = mnew;
      lrun *= ex;
      #pragma unroll
      for (int i = 0; i < 16; ++i) { od0[i] *= ex; od1[i] *= ex; }
    }

    #pragma unroll
    for (int i = 0; i < 16; ++i) s0[i] = EXP2(s0[i] - mrun);
    #pragma unroll
    for (int i = 0; i < 16; ++i) s1[i] = EXP2(s1[i] - mrun);
    float u[16];
    #pragma unroll
    for (int i = 0; i < 16; ++i) u[i] = s0[i] + s1[i];
    #pragma unroll
    for (int off = 8; off > 0; off >>= 1)
      #pragma unroll
      for (int i = 0; i < 8; ++i)
        if (i < off) u[i] = u[i] + u[i + off];
    lrun += xaddf(u[0]);

    bf16x8 pf0, pf1, pf2, pf3;
    {
      u32 a0 = cvtpk(s0[0], s0[1]),   a1 = cvtpk(s0[2], s0[3]);
      u32 b0 = cvtpk(s0[4], s0[5]),   b1 = cvtpk(s0[6], s0[7]);
      plswap(a0, b0); plswap(a1, b1);
      u32 wa[4] = {a0, a1, b0, b1};
      __builtin_memcpy(&pf0, wa, 16);
    }
    {
      u32 a0 = cvtpk(s0[8], s0[9]),   a1 = cvtpk(s0[10], s0[11]);
      u32 b0 = cvtpk(s0[12], s0[13]), b1 = cvtpk(s0[14], s0[15]);
      plswap(a0, b0); plswap(a1, b1);
      u32 wa[4] = {a0, a1, b0, b1};
      __builtin_memcpy(&pf1, wa, 16);
    }
    {
      u32 a0 = cvtpk(s1[0], s1[1]),   a1 = cvtpk(s1[2], s1[3]);
      u32 b0 = cvtpk(s1[4], s1[5]),   b1 = cvtpk(s1[6], s1[7]);
      plswap(a0, b0); plswap(a1, b1);
      u32 wa[4] = {a0, a1, b0, b1};
      __builtin_memcpy(&pf2, wa, 16);
    }
    {
      u32 a0 = cvtpk(s1[8], s1[9]),   a1 = cvtpk(s1[10], s1[11]);
      u32 b0 = cvtpk(s1[12], s1[13]), b1 = cvtpk(s1[14], s1[15]);
      plswap(a0, b0); plswap(a1, b1);
      u32 wa[4] = {a0, a1, b0, b1};
      __builtin_memcpy(&pf3, wa, 16);
    }

    __builtin_amdgcn_s_setprio(1);
    od0 = __builtin_amdgcn_mfma_f32_32x32x16_bf16(vf[0], pf0, od0, 0, 0, 0);
    od0 = __builtin_amdgcn_mfma_f32_32x32x16_bf16(vf[1], pf1, od0, 0, 0, 0);
    od0 = __builtin_amdgcn_mfma_f32_32x32x16_bf16(vf[2], pf2, od0, 0, 0, 0);
    od0 = __builtin_amdgcn_mfma_f32_32x32x16_bf16(vf[3], pf3, od0, 0, 0, 0);
    od1 = __builtin_amdgcn_mfma_f32_32x32x16_bf16(vf[4], pf0, od1, 0, 0, 0);
    od1 = __builtin_amdgcn_mfma_f32_32x32x16_bf16(vf[5], pf1, od1, 0, 0, 0);
    od1 = __builtin_amdgcn_mfma_f32_32x32x16_bf16(vf[6], pf2, od1, 0, 0, 0);
    od1 = __builtin_amdgcn_mfma_f32_32x32x16_bf16(vf[7], pf3, od1, 0, 0, 0);
    __builtin_amdgcn_s_setprio(0);
  };

  // prologue: stage tile tbeg into buffer tbeg&1
  {
    const u16* ks = kb + (size_t)(tbeg*64 + sr)*C3_ + sc;
    const u16* vs = vb + (size_t)sr*T_ + tbeg*64 + sc;
    bf16x8 k0 = *(const bf16x8*)ks, k1 = *(const bf16x8*)(ks + 8);
    bf16x8 v0 = *(const bf16x8*)vs, v1 = *(const bf16x8*)(vs + 8);
    int b0i = tbeg & 1;
    *(bf16x8*)&Kl[b0i][sr][sc] = k0; *(bf16x8*)&Kl[b0i][sr][sc + 8] = k1;
    *(bf16x8*)&Vl[b0i][sr][sc] = v0; *(bf16x8*)&Vl[b0i][sr][sc + 8] = v1;
    __syncthreads();
  }

  for (int t = tbeg; t < tend; ++t) {
    int kv0 = t*64;
    int cb = t & 1, nb = cb ^ 1;
    bool haveNext = (t + 1 < tend);

    bf16x8 nk0, nk1, nv0, nv1;
    if (haveNext) {
      const u16* ks = kb + (size_t)(kv0 + 64 + sr)*C3_ + sc;
      const u16* vs = vb + (size_t)sr*T_ + (kv0 + 64) + sc;
      nk0 = *(const bf16x8*)ks; nk1 = *(const bf16x8*)(ks + 8);
      nv0 = *(const bf16x8*)vs; nv1 = *(const bf16x8*)(vs + 8);
    }

    if (t < ntA) step(qfA, oA0, oA1, mrunA, lrunA, qgA, qr0A, kv0, cb);
    step(qfB, oB0, oB1, mrunB, lrunB, qgB, qr0B, kv0, cb);

    if (haveNext) {
      *(bf16x8*)&Kl[nb][sr][sc] = nk0; *(bf16x8*)&Kl[nb][sr][sc + 8] = nk1;
      *(bf16x8*)&Vl[nb][sr][sc] = nv0; *(bf16x8*)&Vl[nb][sr][sc + 8] = nv1;
    }
    __syncthreads();   // tile t consumed by all; tile t+1 visible to all
  }

  // partial epilogues: write un-normalized O (bf16) + (m,l) per row
  {
    u16* prow = pO + ((size_t)(bidx*T_) + qr0A + l31)*C_ + hh*64;
    #pragma unroll
    for (int r = 0; r < 8; ++r) {
      int dp = ((2*r) & 3) + 8*(r >> 1) + 4*hi;
      *(u32*)(prow + dp)      = cvtpk(oA0[2*r], oA0[2*r+1]);
      *(u32*)(prow + 32 + dp) = cvtpk(oA1[2*r], oA1[2*r+1]);
    }
    if (hi == 0) {
      float* q = pml + (((size_t)(bidx*T_) + qr0A + l31)*H_ + hh)*4 + half*2;
      q[0] = mrunA; q[1] = lrunA;
    }
  }
  {
    u16* prow = pO + ((size_t)(bidx*T_) + qr0B + l31)*C_ + hh*64;
    #pragma unroll
    for (int r = 0; r < 8; ++r) {
      int dp = ((2*r) & 3) + 8*(r >> 1) + 4*hi;
      *(u32*)(prow + dp)      = cvtpk(oB0[2*r], oB0[2*r+1]);
      *(u32*)(prow + 32 + dp) = cvtpk(oB1[2*r], oB1[2*r+1]);
    }
    if (hi == 0) {
      float* q = pml + (((size_t)(bidx*T_) + qr0B + l31)*H_ + hh)*4 + half*2;
      q[0] = mrunB; q[1] = lrunB;
    }
  }
}

// ---------------- merge partial halves: y = (O0*e0 + O1*e1) / (l0*e0 + l1*e1) ----------------
__global__ __launch_bounds__(256) void k_merge(const u16* __restrict__ pO0,
                                               const u16* __restrict__ pO1,
                                               const float* __restrict__ pml,
                                               u16* __restrict__ y) {
  int idx = blockIdx.x * 256 + threadIdx.x;   // one thread per 8 channels
  int row = idx >> 7;                          // C/8 = 128 chunks per row
  int c8 = idx & 127;
  int head = c8 >> 3;
  const float* q = pml + ((size_t)row*H_ + head)*4;
  float m0 = q[0], l0 = q[1], m1 = q[2], l1 = q[3];
  float M = fmaxf(m0, m1);
  float e0 = EXP2(m0 - M), e1 = EXP2(m1 - M);
  float inv = 1.0f / (l0*e0 + l1*e1);
  e0 *= inv; e1 *= inv;
  size_t off = (size_t)idx * 8;
  bf16x8 a = *(const bf16x8*)(pO0 + off);
  bf16x8 b = *(const bf16x8*)(pO1 + off);
  u32 w[4];
  #pragma unroll
  for (int p = 0; p < 4; ++p) {
    float lo = bf2f((u16)a[2*p])     * e0 + bf2f((u16)b[2*p])     * e1;
    float hi = bf2f((u16)a[2*p + 1]) * e0 + bf2f((u16)b[2*p + 1]) * e1;
    w[p] = cvtpk(lo, hi);
  }
  bf16x8 out;
  __builtin_memcpy(&out, w, 16);
  *(bf16x8*)(y + off) = out;
}

extern "C" void kernel_launch(void* const* d_in, const int* in_sizes, int n_in,
                              void* d_out, int out_size, void* d_ws, size_t ws_size,
                              hipStream_t stream) {
  const float* x      = (const float*)d_in[0];
  const float* w_attn = (const float*)d_in[1];
  const float* b_attn = (const float*)d_in[2];
  const float* w_proj = (const float*)d_in[3];
  const float* b_proj = (const float*)d_in[4];

  char* ws = (char*)d_ws;
  size_t off = 0;
  auto walloc = [&](size_t bytes) -> void* {
    void* p = ws + off;
    off += (bytes + 255) & ~(size_t)255;
    return p;
  };
  u16*   xbf  = (u16*)walloc((size_t)BT_ * C_ * 2);   // x bf16; reused as pO0 after gemm0
  u16*   wat  = (u16*)walloc((size_t)C3_ * C_ * 2);   // w_attn^T bf16 [3C][C]
  u16*   wpt  = (u16*)walloc((size_t)C_ * C_ * 2);    // w_proj^T bf16 [C][C]
  u16*   qkv3 = (u16*)walloc((size_t)BT_ * C3_ * 2);  // GEMM0 out [B*T][3C] bf16
  u16*   vT   = (u16*)walloc(BHTD_ * 2);              // V^T [B,H,HD,T]
  u16*   pO1  = (u16*)walloc((size_t)BT_ * C_ * 2);   // partial O half1 (bf16)
  float* pml  = (float*)walloc((size_t)BT_ * H_ * 4 * 4); // [row][H][m0,l0,m1,l1]
  u16*   ybf  = (u16*)walloc((size_t)BT_ * C_ * 2);   // merged attention out (bf16)
  u16*   pO0  = xbf;   // alias: xbf consumed by gemm0 before attention writes partials

  k_prep<<<dim3(12288), 256, 0, stream>>>(x, xbf, w_attn, wat, w_proj, wpt);
  k_gemm<0, C_><<<dim3(C3_/128, BT_/256), 512, 0, stream>>>(xbf, wat, b_attn, (void*)qkv3);
  k_transpose_v<<<dim3(T_/64, B_*H_), 256, 0, stream>>>(qkv3, vT);
  k_attn<<<dim3(1024), 256, 0, stream>>>(qkv3, vT, pO0, pO1, pml);
  k_merge<<<dim3((BT_*C_/8)/256), 256, 0, stream>>>(pO0, pO1, pml, ybf);
  k_gemm<1, C_><<<dim3(C_/128, BT_/256), 512, 0, stream>>>(ybf, wpt, b_proj, d_out);
}

// Round 24
// 165.542 us; speedup vs baseline: 1.1339x; 1.1339x over previous
//
#include <hip/hip_runtime.h>
#include <hip/hip_bf16.h>

#define B_ 4
#define T_ 2048
#define C_ 1024
#define H_ 16
#define HD_ 64
#define BT_ (B_*T_)            // 8192
#define C3_ (3*C_)             // 3072
#define BHTD_ ((size_t)B_*H_*T_*HD_)  // 8388608 elements per q/k/v

// softmax scale 1/8 with log2(e) folded in (attention uses exp2)
#define QSCALE 0.18033688011112042f

using u16 = unsigned short;
using u32 = unsigned int;
using bf16x8 = __attribute__((ext_vector_type(8))) short;
using f32x4  = __attribute__((ext_vector_type(4))) float;
using f32x16 = __attribute__((ext_vector_type(16))) float;
using u16x4  = __attribute__((ext_vector_type(4))) u16;
typedef int i32x2 __attribute__((ext_vector_type(2)));

#if __has_builtin(__builtin_amdgcn_exp2f)
#define EXP2(x) __builtin_amdgcn_exp2f(x)
#else
#define EXP2(x) exp2f(x)
#endif

__device__ __forceinline__ u16 f2bf(float f) {
  u32 u = __float_as_uint(f);
  u += 0x7fffu + ((u >> 16) & 1u);   // round-to-nearest-even
  return (u16)(u >> 16);
}

// v_cvt_pk_bf16_f32: one instruction packs two f32 -> two bf16 (RTNE)
__device__ __forceinline__ u32 cvtpk(float lo, float hi) {
  u32 r;
  asm("v_cvt_pk_bf16_f32 %0, %1, %2" : "=v"(r) : "v"(lo), "v"(hi));
  return r;
}

// exchange with the lane^32 partner
__device__ __forceinline__ void plswap(u32 &a, u32 &b) {
#if __has_builtin(__builtin_amdgcn_permlane32_swap)
  i32x2 r = __builtin_amdgcn_permlane32_swap((int)a, (int)b, false, false);
  a = (u32)r[0]; b = (u32)r[1];
#else
  asm volatile("v_permlane32_swap_b32 %0, %1" : "+v"(a), "+v"(b));
#endif
}

__device__ __forceinline__ float xmaxf(float x) {
  u32 a = __float_as_uint(x), b = a;
  plswap(a, b);
  return fmaxf(__uint_as_float(a), __uint_as_float(b));
}
__device__ __forceinline__ float xaddf(float x) {
  u32 a = __float_as_uint(x), b = a;
  plswap(a, b);
  return __uint_as_float(a) + __uint_as_float(b);
}

__device__ __forceinline__ void gload16(const void* g,
                                        __attribute__((address_space(3))) void* l) {
  __builtin_amdgcn_global_load_lds((const __attribute__((address_space(1))) void*)g,
                                   l, 16, 0, 0);
}

// ---------------- fused prep: x->bf16  +  w_attn^T  +  w_proj^T (one launch) ----------------
__global__ __launch_bounds__(256) void k_prep(const float* __restrict__ x,
                                              u16* __restrict__ xbf,
                                              const float* __restrict__ w_attn,
                                              u16* __restrict__ wat,
                                              const float* __restrict__ w_proj,
                                              u16* __restrict__ wpt) {
  __shared__ float t[32][33];
  int fb = blockIdx.x;
  if (fb < 8192) {
    size_t i = ((size_t)fb * 256 + threadIdx.x) * 4;
    f32x4 f = *(const f32x4*)(x + i);
    u16x4 o;
    o[0] = f2bf(f[0]); o[1] = f2bf(f[1]); o[2] = f2bf(f[2]); o[3] = f2bf(f[3]);
    *(u16x4*)(xbf + i) = o;
    return;
  }
  const float* w; u16* wt; int K, N, n0, k0;
  if (fb < 8192 + 3072) {
    int tb = fb - 8192;
    w = w_attn; wt = wat; K = C_; N = C3_;
    n0 = (tb % 96) * 32; k0 = (tb / 96) * 32;
  } else {
    int tb = fb - 8192 - 3072;
    w = w_proj; wt = wpt; K = C_; N = C_;
    n0 = (tb % 32) * 32; k0 = (tb / 32) * 32;
  }
  int tx = threadIdx.x & 31;
  int ty = threadIdx.x >> 5;   // 0..7
  #pragma unroll
  for (int r = 0; r < 4; ++r)
    t[ty + r*8][tx] = w[(size_t)(k0 + ty + r*8) * N + n0 + tx];
  __syncthreads();
  #pragma unroll
  for (int r = 0; r < 4; ++r)
    wt[(size_t)(n0 + ty + r*8) * K + k0 + tx] = f2bf(t[tx][ty + r*8]);
}

// ---------------- transpose V: qkv3[B*T][3C] (V slice) -> vT [B,H,HD,T] ----------------
__global__ __launch_bounds__(256) void k_transpose_v(const u16* __restrict__ qkv3,
                                                     u16* __restrict__ dst) {
  __shared__ u16 t[64][72];
  int bh = blockIdx.y;
  int bb = bh >> 4, hh = bh & 15;
  int t0 = blockIdx.x * 64;
  const u16* s = qkv3 + (size_t)(bb*T_)*C3_ + 2*C_ + hh*64;   // V slice, row stride 3C
  u16* d = dst + (size_t)bh * HD_ * T_;
  int r = threadIdx.x >> 2, c0 = (threadIdx.x & 3) * 16;
  bf16x8 a0 = *(const bf16x8*)(s + (size_t)(t0 + r)*C3_ + c0);
  bf16x8 a1 = *(const bf16x8*)(s + (size_t)(t0 + r)*C3_ + c0 + 8);
  #pragma unroll
  for (int j = 0; j < 8; ++j) t[r][c0 + j] = (u16)a0[j];
  #pragma unroll
  for (int j = 0; j < 8; ++j) t[r][c0 + 8 + j] = (u16)a1[j];
  __syncthreads();
  bf16x8 b0, b1;
  #pragma unroll
  for (int j = 0; j < 8; ++j) b0[j] = (short)t[c0 + j][r];
  #pragma unroll
  for (int j = 0; j < 8; ++j) b1[j] = (short)t[c0 + 8 + j][r];
  *(bf16x8*)(d + (size_t)r*T_ + t0 + c0) = b0;
  *(bf16x8*)(d + (size_t)r*T_ + t0 + c0 + 8) = b1;
}

// ---------------- bf16 MFMA GEMM: 256x128 tile, BK=64, 8 waves (validated r22) ----------------
template<int EPI, int K>
__global__ __launch_bounds__(512) void k_gemm(const u16* __restrict__ A,
                                              const u16* __restrict__ Bt,
                                              const float* __restrict__ bias,
                                              void* __restrict__ outp) {
  __shared__ __align__(16) u16 lA[256*64];   // 32 KB
  __shared__ __align__(16) u16 lB[128*64];   // 16 KB
  int tid = threadIdx.x;
  int wave = tid >> 6, lane = tid & 63;
  int wr = wave >> 1, wc = wave & 1;         // wr 0..3 (rows), wc 0..1 (cols)
  int lrow = lane & 15, lgrp = lane >> 4;
  int bidf = blockIdx.y * gridDim.x + blockIdx.x;
  int xcd = bidf & 7, loc = bidf >> 3;       // consecutive blocks round-robin XCDs
  int ypx = gridDim.y >> 3;                  // by-rows per XCD chunk
  int bx = loc / ypx;                        // column-major within chunk
  int by = xcd * ypx + (loc % ypx);
  int row0 = by * 256, col0 = bx * 128;

  f32x4 zero = {0.f, 0.f, 0.f, 0.f};
  f32x4 acc[4][4];
  #pragma unroll
  for (int m = 0; m < 4; ++m)
    #pragma unroll
    for (int n = 0; n < 4; ++n) acc[m][n] = zero;

  for (int kt = 0; kt < K; kt += 64) {
    #pragma unroll
    for (int it = 0; it < 4; ++it) {
      int c = tid + it*512;             // 16B chunk 0..2047
      int r = c >> 3, sl = c & 7;       // row, logical slot
      int sk = sl ^ (r & 7);            // pre-swizzled SOURCE slot (LDS linear)
      gload16(A + (size_t)(row0 + r)*K + kt + sk*8,
              (__attribute__((address_space(3))) char*)lA + it*8192 + wave*1024);
    }
    #pragma unroll
    for (int it = 0; it < 2; ++it) {
      int c = tid + it*512;             // 16B chunk 0..1023
      int r = c >> 3, sl = c & 7;
      int sk = sl ^ (r & 7);
      gload16(Bt + (size_t)(col0 + r)*K + kt + sk*8,
              (__attribute__((address_space(3))) char*)lB + it*8192 + wave*1024);
    }
    __syncthreads();
    #pragma unroll
    for (int kk = 0; kk < 2; ++kk) {
      bf16x8 af[4], bfr[4];
      #pragma unroll
      for (int m = 0; m < 4; ++m) {
        int row = wr*64 + m*16 + lrow;
        af[m] = *(const bf16x8*)(lA + row*64 + (((kk*4 + lgrp) ^ (row & 7)))*8);
      }
      #pragma unroll
      for (int n = 0; n < 4; ++n) {
        int row = wc*64 + n*16 + lrow;
        bfr[n] = *(const bf16x8*)(lB + row*64 + (((kk*4 + lgrp) ^ (row & 7)))*8);
      }
      #pragma unroll
      for (int m = 0; m < 4; ++m)
        #pragma unroll
        for (int n = 0; n < 4; ++n)
          acc[m][n] = __builtin_amdgcn_mfma_f32_16x16x32_bf16(af[m], bfr[n], acc[m][n], 0, 0, 0);
    }
    __syncthreads();
  }

  #pragma unroll
  for (int m = 0; m < 4; ++m) {
    #pragma unroll
    for (int n = 0; n < 4; ++n) {
      int gcol = col0 + wc*64 + n*16 + lrow;
      float bv = bias[gcol];
      #pragma unroll
      for (int r = 0; r < 4; ++r) {
        int grow = row0 + wr*64 + m*16 + lgrp*4 + r;
        float val = acc[m][n][r] + bv;
        if (EPI == 0) {
          if (gcol < C_) val *= QSCALE;   // fold softmax scale * log2(e) into q
          ((u16*)outp)[(size_t)grow*C3_ + gcol] = f2bf(val);   // coalesced [M][3C]
        } else {
          ((float*)outp)[(size_t)grow*C_ + gcol] = val;
        }
      }
    }
  }
}

// ---------------- causal flash attention: LDS-shared K/V, shared tile stream ----------------
// (r21/r22-validated: 512 blocks x 4 waves; q-tile pair (jA,15-jA) shares ONE staged
// tile stream; reg-staged double-buffer + plain __syncthreads; T14 issue-early.)
__global__ __launch_bounds__(256, 2) void k_attn(const u16* __restrict__ qkv3,
                                                 const u16* __restrict__ vt,
                                                 u16* __restrict__ y) {
  __shared__ __align__(16) u16 Kl[2][64][72];   // 18.4 KB (padded rows)
  __shared__ __align__(16) u16 Vl[2][64][72];   // 18.4 KB
  int tid = threadIdx.x;
  int wave = tid >> 6, lane = tid & 63;
  int l31 = lane & 31, hi = lane >> 5;
  int bid = blockIdx.x;
  int head = bid & 63;                 // bid&7 = head&7 -> stable XCD group per head
  int jA = bid >> 6;                   // 0..7 -> pair (jA, 15-jA)
  int jB = 15 - jA;
  int bidx = head >> 4, hh = head & 15;
  const u16* qb = qkv3 + (size_t)(bidx*T_)*C3_ + hh*64;        // row stride 3C
  const u16* kb = qkv3 + (size_t)(bidx*T_)*C3_ + C_ + hh*64;   // row stride 3C
  const u16* vb = vt + (size_t)head * HD_ * T_;                // [HD][T]

  int sr = tid >> 2;            // staging row 0..63
  int sc = (tid & 3) * 16;      // staging col (u16 units)

  f32x16 zero16 = {0.f,0.f,0.f,0.f,0.f,0.f,0.f,0.f,0.f,0.f,0.f,0.f,0.f,0.f,0.f,0.f};

  int qr0A = jA*128 + wave*32, qr0B = jB*128 + wave*32;
  bf16x8 qfA[4], qfB[4];
  {
    const u16* qrowA = qb + (size_t)(qr0A + l31)*C3_ + hi*8;
    const u16* qrowB = qb + (size_t)(qr0B + l31)*C3_ + hi*8;
    #pragma unroll
    for (int i = 0; i < 4; ++i) { qfA[i] = *(const bf16x8*)(qrowA + 16*i);
                                  qfB[i] = *(const bf16x8*)(qrowB + 16*i); }
  }
  f32x16 oA0 = zero16, oA1 = zero16, oB0 = zero16, oB1 = zero16;
  float mrunA = -1e30f, lrunA = 0.f, mrunB = -1e30f, lrunB = 0.f;
  int qgA = qr0A + l31, qgB = qr0B + l31;
  int ntA = 2*jA + 2, ntB = 2*jB + 2;   // ntB > ntA (jA<8)

  auto step = [&](bf16x8 (&qf)[4], f32x16 &od0, f32x16 &od1,
                  float &mrun, float &lrun, int qg, int qr0, int kv0, int cb) {
    if (kv0 > qr0 + 31) return;          // wave-uniform: fully-masked tile
    bf16x8 kf[8], vf[8];
    #pragma unroll
    for (int i = 0; i < 4; ++i) {
      int cc = 16*i + 8*hi;
      kf[i]     = *(const bf16x8*)&Kl[cb][l31][cc];
      kf[4 + i] = *(const bf16x8*)&Kl[cb][l31 + 32][cc];
      vf[i]     = *(const bf16x8*)&Vl[cb][l31][cc];
      vf[4 + i] = *(const bf16x8*)&Vl[cb][l31 + 32][cc];
    }

    f32x16 s0 = zero16, s1 = zero16;
    __builtin_amdgcn_s_setprio(1);
    s0 = __builtin_amdgcn_mfma_f32_32x32x16_bf16(kf[0], qf[0], s0, 0, 0, 0);
    s1 = __builtin_amdgcn_mfma_f32_32x32x16_bf16(kf[4], qf[0], s1, 0, 0, 0);
    s0 = __builtin_amdgcn_mfma_f32_32x32x16_bf16(kf[1], qf[1], s0, 0, 0, 0);
    s1 = __builtin_amdgcn_mfma_f32_32x32x16_bf16(kf[5], qf[1], s1, 0, 0, 0);
    s0 = __builtin_amdgcn_mfma_f32_32x32x16_bf16(kf[2], qf[2], s0, 0, 0, 0);
    s1 = __builtin_amdgcn_mfma_f32_32x32x16_bf16(kf[6], qf[2], s1, 0, 0, 0);
    s0 = __builtin_amdgcn_mfma_f32_32x32x16_bf16(kf[3], qf[3], s0, 0, 0, 0);
    s1 = __builtin_amdgcn_mfma_f32_32x32x16_bf16(kf[7], qf[3], s1, 0, 0, 0);
    __builtin_amdgcn_s_setprio(0);

    if (kv0 + 63 > qr0) {      // diagonal tile: apply causal mask
      #pragma unroll
      for (int r = 0; r < 16; ++r) {
        int kl2 = (r & 3) + 8*(r >> 2) + 4*hi;
        if (kv0 + kl2      > qg) s0[r] = -1e30f;
        if (kv0 + 32 + kl2 > qg) s1[r] = -1e30f;
      }
    }

    float tmx[16];
    #pragma unroll
    for (int i = 0; i < 16; ++i) tmx[i] = fmaxf(s0[i], s1[i]);
    #pragma unroll
    for (int off = 8; off > 0; off >>= 1)
      #pragma unroll
      for (int i = 0; i < 8; ++i)
        if (i < off) tmx[i] = fmaxf(tmx[i], tmx[i + off]);
    float pmax = xmaxf(tmx[0]);

    if (!__all(pmax <= mrun)) {
      float mnew = fmaxf(mrun, pmax);
      float ex = EXP2(mrun - mnew);
      mrun = mnew;
      lrun *= ex;
      #pragma unroll
      for (int i = 0; i < 16; ++i) { od0[i] *= ex; od1[i] *= ex; }
    }

    #pragma unroll
    for (int i = 0; i < 16; ++i) s0[i] = EXP2(s0[i] - mrun);
    #pragma unroll
    for (int i = 0; i < 16; ++i) s1[i] = EXP2(s1[i] - mrun);
    float u[16];
    #pragma unroll
    for (int i = 0; i < 16; ++i) u[i] = s0[i] + s1[i];
    #pragma unroll
    for (int off = 8; off > 0; off >>= 1)
      #pragma unroll
      for (int i = 0; i < 8; ++i)
        if (i < off) u[i] = u[i] + u[i + off];
    lrun += xaddf(u[0]);

    bf16x8 pf0, pf1, pf2, pf3;
    {
      u32 a0 = cvtpk(s0[0], s0[1]),   a1 = cvtpk(s0[2], s0[3]);
      u32 b0 = cvtpk(s0[4], s0[5]),   b1 = cvtpk(s0[6], s0[7]);
      plswap(a0, b0); plswap(a1, b1);
      u32 wa[4] = {a0, a1, b0, b1};
      __builtin_memcpy(&pf0, wa, 16);
    }
    {
      u32 a0 = cvtpk(s0[8], s0[9]),   a1 = cvtpk(s0[10], s0[11]);
      u32 b0 = cvtpk(s0[12], s0[13]), b1 = cvtpk(s0[14], s0[15]);
      plswap(a0, b0); plswap(a1, b1);
      u32 wa[4] = {a0, a1, b0, b1};
      __builtin_memcpy(&pf1, wa, 16);
    }
    {
      u32 a0 = cvtpk(s1[0], s1[1]),   a1 = cvtpk(s1[2], s1[3]);
      u32 b0 = cvtpk(s1[4], s1[5]),   b1 = cvtpk(s1[6], s1[7]);
      plswap(a0, b0); plswap(a1, b1);
      u32 wa[4] = {a0, a1, b0, b1};
      __builtin_memcpy(&pf2, wa, 16);
    }
    {
      u32 a0 = cvtpk(s1[8], s1[9]),   a1 = cvtpk(s1[10], s1[11]);
      u32 b0 = cvtpk(s1[12], s1[13]), b1 = cvtpk(s1[14], s1[15]);
      plswap(a0, b0); plswap(a1, b1);
      u32 wa[4] = {a0, a1, b0, b1};
      __builtin_memcpy(&pf3, wa, 16);
    }

    __builtin_amdgcn_s_setprio(1);
    od0 = __builtin_amdgcn_mfma_f32_32x32x16_bf16(vf[0], pf0, od0, 0, 0, 0);
    od0 = __builtin_amdgcn_mfma_f32_32x32x16_bf16(vf[1], pf1, od0, 0, 0, 0);
    od0 = __builtin_amdgcn_mfma_f32_32x32x16_bf16(vf[2], pf2, od0, 0, 0, 0);
    od0 = __builtin_amdgcn_mfma_f32_32x32x16_bf16(vf[3], pf3, od0, 0, 0, 0);
    od1 = __builtin_amdgcn_mfma_f32_32x32x16_bf16(vf[4], pf0, od1, 0, 0, 0);
    od1 = __builtin_amdgcn_mfma_f32_32x32x16_bf16(vf[5], pf1, od1, 0, 0, 0);
    od1 = __builtin_amdgcn_mfma_f32_32x32x16_bf16(vf[6], pf2, od1, 0, 0, 0);
    od1 = __builtin_amdgcn_mfma_f32_32x32x16_bf16(vf[7], pf3, od1, 0, 0, 0);
    __builtin_amdgcn_s_setprio(0);
  };

  // prologue: stage tile 0 into buffer 0
  {
    const u16* ks = kb + (size_t)sr*C3_ + sc;
    const u16* vs = vb + (size_t)sr*T_ + sc;
    bf16x8 k0 = *(const bf16x8*)ks, k1 = *(const bf16x8*)(ks + 8);
    bf16x8 v0 = *(const bf16x8*)vs, v1 = *(const bf16x8*)(vs + 8);
    *(bf16x8*)&Kl[0][sr][sc] = k0; *(bf16x8*)&Kl[0][sr][sc + 8] = k1;
    *(bf16x8*)&Vl[0][sr][sc] = v0; *(bf16x8*)&Vl[0][sr][sc + 8] = v1;
    __syncthreads();
  }

  for (int t = 0; t < ntB; ++t) {
    int kv0 = t*64;
    int cb = t & 1, nb = cb ^ 1;
    bool haveNext = (t + 1 < ntB);

    bf16x8 nk0, nk1, nv0, nv1;
    if (haveNext) {
      const u16* ks = kb + (size_t)(kv0 + 64 + sr)*C3_ + sc;
      const u16* vs = vb + (size_t)sr*T_ + (kv0 + 64) + sc;
      nk0 = *(const bf16x8*)ks; nk1 = *(const bf16x8*)(ks + 8);
      nv0 = *(const bf16x8*)vs; nv1 = *(const bf16x8*)(vs + 8);
    }

    if (t < ntA) step(qfA, oA0, oA1, mrunA, lrunA, qgA, qr0A, kv0, cb);
    step(qfB, oB0, oB1, mrunB, lrunB, qgB, qr0B, kv0, cb);

    if (haveNext) {
      *(bf16x8*)&Kl[nb][sr][sc] = nk0; *(bf16x8*)&Kl[nb][sr][sc + 8] = nk1;
      *(bf16x8*)&Vl[nb][sr][sc] = nv0; *(bf16x8*)&Vl[nb][sr][sc + 8] = nv1;
    }
    __syncthreads();   // tile t consumed by all; tile t+1 visible to all
  }

  // epilogues
  {
    float inv = 1.0f / lrunA;
    u16* yrow = y + ((size_t)(bidx*T_) + qr0A + l31)*C_ + hh*64;
    #pragma unroll
    for (int r = 0; r < 8; ++r) {
      int dp = ((2*r) & 3) + 8*(r >> 1) + 4*hi;
      *(u32*)(yrow + dp)      = cvtpk(oA0[2*r]*inv, oA0[2*r+1]*inv);
      *(u32*)(yrow + 32 + dp) = cvtpk(oA1[2*r]*inv, oA1[2*r+1]*inv);
    }
  }
  {
    float inv = 1.0f / lrunB;
    u16* yrow = y + ((size_t)(bidx*T_) + qr0B + l31)*C_ + hh*64;
    #pragma unroll
    for (int r = 0; r < 8; ++r) {
      int dp = ((2*r) & 3) + 8*(r >> 1) + 4*hi;
      *(u32*)(yrow + dp)      = cvtpk(oB0[2*r]*inv, oB0[2*r+1]*inv);
      *(u32*)(yrow + 32 + dp) = cvtpk(oB1[2*r]*inv, oB1[2*r+1]*inv);
    }
  }
}

extern "C" void kernel_launch(void* const* d_in, const int* in_sizes, int n_in,
                              void* d_out, int out_size, void* d_ws, size_t ws_size,
                              hipStream_t stream) {
  const float* x      = (const float*)d_in[0];
  const float* w_attn = (const float*)d_in[1];
  const float* b_attn = (const float*)d_in[2];
  const float* w_proj = (const float*)d_in[3];
  const float* b_proj = (const float*)d_in[4];

  char* ws = (char*)d_ws;
  size_t off = 0;
  auto walloc = [&](size_t bytes) -> void* {
    void* p = ws + off;
    off += (bytes + 255) & ~(size_t)255;
    return p;
  };
  u16* xbf  = (u16*)walloc((size_t)BT_ * C_ * 2);     // x as bf16; later reused as y
  u16* wat  = (u16*)walloc((size_t)C3_ * C_ * 2);     // w_attn^T bf16 [3C][C]
  u16* wpt  = (u16*)walloc((size_t)C_ * C_ * 2);      // w_proj^T bf16 [C][C]
  u16* qkv3 = (u16*)walloc((size_t)BT_ * C3_ * 2);    // GEMM0 out [B*T][3C] bf16
  u16* vT   = (u16*)walloc(BHTD_ * 2);                // V^T [B,H,HD,T]
  u16* ybf = xbf;   // alias: x consumed by GEMM1 before attention writes y

  k_prep<<<dim3(12288), 256, 0, stream>>>(x, xbf, w_attn, wat, w_proj, wpt);
  k_gemm<0, C_><<<dim3(C3_/128, BT_/256), 512, 0, stream>>>(xbf, wat, b_attn, (void*)qkv3);
  k_transpose_v<<<dim3(T_/64, B_*H_), 256, 0, stream>>>(qkv3, vT);
  k_attn<<<dim3(512), 256, 0, stream>>>(qkv3, vT, ybf);
  k_gemm<1, C_><<<dim3(C_/128, BT_/256), 512, 0, stream>>>(ybf, wpt, b_proj, d_out);
}